// Round 6
// baseline (112.622 us; speedup 1.0000x reference)
//
#include <hip/hip_runtime.h>

typedef float float2v __attribute__((ext_vector_type(2)));
typedef float float4v __attribute__((ext_vector_type(4)));

#define NN 1024

// ---------------- K1: fused ac1 + pair32(relu, pk-f32) + ac2 ----------------
// 512 blocks x 256. Wave owns row i = blk*4+wave.
// x batch (12 KB) staged to LDS once; c1-tiles recomputed from LDS-x (pk);
// j-loop 4-way js split, float2 lanes. Epilogue: row @ W2 -> a2,c2.
// Block 0 also zeroes k2's completion counter.
__global__ __launch_bounds__(256) void k1_pair32_ac2(
    const float* __restrict__ x,  const float* __restrict__ W1, const float* __restrict__ b1,
    const float* __restrict__ W2, const float* __restrict__ b2,
    float* __restrict__ a2g, float* __restrict__ c2g, unsigned int* __restrict__ counter)
{
    __shared__ float xbuf[3072];        // whole batch x, 12 KB
    __shared__ float cbuf[8192];        // 256 rows x 32, 32 KB
    __shared__ float rowbuf[4][32];

    const int tid  = threadIdx.x;
    const int wave = tid >> 6, lane = tid & 63;
    const int blk  = blockIdx.x;
    if (blk == 0 && tid == 0) *counter = 0u;

    const int i  = blk * 4 + wave;      // 0..2047
    const int b  = i >> 10;
    const int il = i & 1023;
    const int js = lane >> 4;           // 0..3 (j-quarter)
    const int fp = lane & 15;           // f-pair index (f = 2fp, 2fp+1)

    // stage x batch to LDS
    const float4v* xb4 = (const float4v*)(x + b * 3072);
    {
        float4v* xd = (float4v*)xbuf;
        #pragma unroll
        for (int n = 0; n < 3; ++n) xd[tid + n * 256] = xb4[tid + n * 256];
    }
    __syncthreads();

    const float xi0 = xbuf[il*3+0], xi1 = xbuf[il*3+1], xi2 = xbuf[il*3+2];
    const float2v* W1v = (const float2v*)W1;
    const float2v* b1v = (const float2v*)b1;
    float2v a  = xi0*W1v[0*16+fp] + xi1*W1v[1*16+fp] + xi2*W1v[2*16+fp];
    float2v cs = xi0*W1v[3*16+fp] + xi1*W1v[4*16+fp] + xi2*W1v[5*16+fp] + b1v[fp];

    // c-recompute assignment: thread (fp2, r0); rows r = r0 + k*16 within tile
    const int fp2 = tid & 15, r0 = tid >> 4;
    const float2v w3 = W1v[3*16+fp2], w4 = W1v[4*16+fp2], w5 = W1v[5*16+fp2];
    const float2v bb = b1v[fp2];

    float2v acc = (float2v)0.f;
    float2v* cb2w = (float2v*)cbuf;
    const float2v* cb2 = (const float2v*)cbuf;
    for (int tile = 0; tile < NN; tile += 256) {
        #pragma unroll
        for (int k = 0; k < 16; ++k) {
            int r = r0 + k * 16;
            int g = tile + r;
            float y0 = xbuf[g*3+0], y1 = xbuf[g*3+1], y2 = xbuf[g*3+2];
            cb2w[r*16 + fp2] = y0*w3 + y1*w4 + y2*w5 + bb;
        }
        __syncthreads();
        #pragma unroll 8
        for (int k = 0; k < 64; ++k) {
            float2v c = cb2[(4*k + js)*16 + fp];
            acc += __builtin_elementwise_max(a + c, (float2v)0.f);
        }
        __syncthreads();
    }
    // reduce across the 4 js groups (lane bits 4,5)
    acc.x += __shfl_xor(acc.x, 16);  acc.y += __shfl_xor(acc.y, 16);
    acc.x += __shfl_xor(acc.x, 32);  acc.y += __shfl_xor(acc.y, 32);

    float2v self = __builtin_elementwise_max(a + cs, (float2v)0.f);
    float2v res  = (acc - self) * (1.0f/1023.0f);
    if (js == 0) ((float2v*)rowbuf[wave])[fp] = res;
    __syncthreads();

    // ---- ac2 epilogue: h-row (32) @ W2 (64x64) + b2 ----
    float av = 0.f, cv = b2[lane];
    #pragma unroll
    for (int d = 0; d < 32; ++d) {
        float hv = rowbuf[wave][d];     // LDS broadcast
        av += hv * W2[d*64 + lane];
        cv += hv * W2[(32 + d)*64 + lane];
    }
    a2g[i*64 + lane] = av;
    c2g[i*64 + lane] = cv;
}

// ---------------- K2: pair-sum F=64 (pk-f32) + final projection + last-block S ----------------
// 256 blocks x 256. Block owns rows i0..i0+7; wave owns rows rA=i0+2w, rB=rA+1.
// lane = jh*32+fp: j-half jh, f-pair fp. Double-buffered reg staging of c2 tiles.
// Last block (atomic counter) reduces partials -> S and RMW-adds S/1023 to out.
__global__ __launch_bounds__(256) void k2_pair64_final(
    const float* __restrict__ a2g, const float* __restrict__ c2g,
    const float* __restrict__ W3, const float* __restrict__ b3,
    float* __restrict__ out, float* __restrict__ partials, unsigned int* __restrict__ counter)
{
    __shared__ float cbuf[8192];        // 128 j-rows x 64 f, 32 KB
    __shared__ float qpart[4][3];
    __shared__ float red[4][3];
    __shared__ unsigned int sLast;

    const int tid  = threadIdx.x;
    const int wave = tid >> 6, lane = tid & 63;
    const int blk  = blockIdx.x;        // 0..255

    const int i0 = blk * 8;
    const int b  = blk >> 7;            // batch
    const int jh = lane >> 5, fp = lane & 31;
    const int rA = i0 + 2*wave, rB = rA + 1;

    const float* cb = c2g + b * (NN * 64);
    const float2v* a2v = (const float2v*)a2g;
    const float2v aA = a2v[rA*32 + fp];
    const float2v aB = a2v[rB*32 + fp];
    float2v acc0 = (float2v)0.f, acc1 = (float2v)0.f;

    const float4v* src = (const float4v*)cb;    // 16 float4 per j-row
    float4v regs[8];
    // stage tile 0
    #pragma unroll
    for (int n = 0; n < 8; ++n) regs[n] = src[tid + n*256];
    {
        float4v* dst = (float4v*)cbuf;
        #pragma unroll
        for (int n = 0; n < 8; ++n) dst[tid + n*256] = regs[n];
    }
    __syncthreads();

    const float2v* cb2 = (const float2v*)cbuf;
    for (int tile = 0; tile < NN; tile += 128) {
        const bool more = (tile + 128) < NN;
        if (more) {
            const float4v* s2 = src + (tile + 128) * 16;
            #pragma unroll
            for (int n = 0; n < 8; ++n) regs[n] = s2[tid + n*256];
        }
        #pragma unroll 8
        for (int k = 0; k < 64; ++k) {
            float2v c = cb2[(2*k + jh)*32 + fp];
            acc0 += __builtin_elementwise_max(aA + c, (float2v)0.f);
            acc1 += __builtin_elementwise_max(aB + c, (float2v)0.f);
        }
        __syncthreads();
        if (more) {
            float4v* dst = (float4v*)cbuf;
            #pragma unroll
            for (int n = 0; n < 8; ++n) dst[tid + n*256] = regs[n];
        }
        __syncthreads();
    }
    // combine j-halves (lane bit 5); both halves then hold identical full sums
    acc0.x += __shfl_xor(acc0.x, 32);  acc0.y += __shfl_xor(acc0.y, 32);
    acc1.x += __shfl_xor(acc1.x, 32);  acc1.y += __shfl_xor(acc1.y, 32);

    const float2v* cbv = (const float2v*)cb;
    const float inv = 1.0f/1023.0f;
    float2v res0 = (acc0 - __builtin_elementwise_max(aA + cbv[(rA & 1023)*32 + fp], (float2v)0.f)) * inv;
    float2v res1 = (acc1 - __builtin_elementwise_max(aB + cbv[(rB & 1023)*32 + fp], (float2v)0.f)) * inv;

    // final projection: per-lane f-pair, butterfly within 32-lane halves (no xor 32:
    // both halves hold identical res, each half sums its own 32 fp -> full sum)
    float yA[3], qA[3], yB[3], qB[3];
    #pragma unroll
    for (int t = 0; t < 3; ++t) {
        float wt0 = W3[(2*fp)*3 + t],   wb0 = W3[(64 + 2*fp)*3 + t];
        float wt1 = W3[(2*fp+1)*3 + t], wb1 = W3[(64 + 2*fp+1)*3 + t];
        float k0 = wt0 - wb0*inv, k1 = wt1 - wb1*inv;
        yA[t] = res0.x*k0 + res0.y*k1;   qA[t] = res0.x*wb0 + res0.y*wb1;
        yB[t] = res1.x*k0 + res1.y*k1;   qB[t] = res1.x*wb0 + res1.y*wb1;
    }
    #pragma unroll
    for (int off = 1; off < 32; off <<= 1) {
        #pragma unroll
        for (int t = 0; t < 3; ++t) {
            yA[t] += __shfl_xor(yA[t], off);  qA[t] += __shfl_xor(qA[t], off);
            yB[t] += __shfl_xor(yB[t], off);  qB[t] += __shfl_xor(qB[t], off);
        }
    }
    if (lane == 0) {
        out[rA*3+0] = yA[0] + b3[0];  out[rA*3+1] = yA[1] + b3[1];  out[rA*3+2] = yA[2] + b3[2];
        out[rB*3+0] = yB[0] + b3[0];  out[rB*3+1] = yB[1] + b3[1];  out[rB*3+2] = yB[2] + b3[2];
        qpart[wave][0] = qA[0] + qB[0];
        qpart[wave][1] = qA[1] + qB[1];
        qpart[wave][2] = qA[2] + qB[2];
    }
    __syncthreads();
    if (tid < 3)
        partials[blk*3 + tid] = qpart[0][tid] + qpart[1][tid] + qpart[2][tid] + qpart[3][tid];

    // ---- last-block completion sync ----
    __threadfence();                    // release: each thread's out/partials writes
    __syncthreads();                    // block-wide: fences done before signal
    if (tid == 0) sLast = (atomicAdd(counter, 1u) == 255u) ? 1u : 0u;
    __syncthreads();
    if (!sLast) return;
    __threadfence();                    // acquire

    // reduce partials: blocks 0..127 batch0, 128..255 batch1
    {
        const int half = tid >> 7, kk = tid & 127;   // waves 0,1 = batch0; 2,3 = batch1
        const float* pp = partials + (half*128 + kk) * 3;
        float p0 = pp[0], p1 = pp[1], p2 = pp[2];
        #pragma unroll
        for (int off = 1; off < 64; off <<= 1) {
            p0 += __shfl_xor(p0, off);  p1 += __shfl_xor(p1, off);  p2 += __shfl_xor(p2, off);
        }
        if (lane == 0) { red[wave][0] = p0; red[wave][1] = p1; red[wave][2] = p2; }
    }
    __syncthreads();
    float S[2][3];
    #pragma unroll
    for (int t = 0; t < 3; ++t) {
        S[0][t] = (red[0][t] + red[1][t]) * inv;
        S[1][t] = (red[2][t] + red[3][t]) * inv;
    }
    // RMW out: 1536 float4 (768 per batch); component pattern period 3 in float4 index
    float4v addv[2][3];
    #pragma unroll
    for (int bb = 0; bb < 2; ++bb) {
        addv[bb][0] = (float4v){S[bb][0], S[bb][1], S[bb][2], S[bb][0]};
        addv[bb][1] = (float4v){S[bb][1], S[bb][2], S[bb][0], S[bb][1]};
        addv[bb][2] = (float4v){S[bb][2], S[bb][0], S[bb][1], S[bb][2]};
    }
    float4v* o4 = (float4v*)out;
    #pragma unroll
    for (int n = 0; n < 6; ++n) {
        int idx = tid + n * 256;
        o4[idx] += addv[idx >> 9 ? (idx / 768) : 0][idx % 3];
    }
}

extern "C" void kernel_launch(void* const* d_in, const int* in_sizes, int n_in,
                              void* d_out, int out_size, void* d_ws, size_t ws_size,
                              hipStream_t stream) {
    const float* x  = (const float*)d_in[0];
    const float* W1 = (const float*)d_in[1];
    const float* b1 = (const float*)d_in[2];
    const float* W2 = (const float*)d_in[3];
    const float* b2 = (const float*)d_in[4];
    const float* W3 = (const float*)d_in[5];
    const float* b3 = (const float*)d_in[6];
    float* out = (float*)d_out;

    float* ws = (float*)d_ws;
    float* a2g        = ws;                    // 131072 floats
    float* c2g        = a2g + 131072;          // 131072 floats (512 KB offset, 16B aligned)
    float* partials   = c2g + 131072;          // 768 floats
    unsigned int* cnt = (unsigned int*)(partials + 768);

    k1_pair32_ac2<<<512, 256, 0, stream>>>(x, W1, b1, W2, b2, a2g, c2g, cnt);
    k2_pair64_final<<<256, 256, 0, stream>>>(a2g, c2g, W3, b3, out, partials, cnt);
}

// Round 7
// 104.663 us; speedup vs baseline: 1.0760x; 1.0760x over previous
//
#include <hip/hip_runtime.h>

typedef float float2v __attribute__((ext_vector_type(2)));
typedef float float4v __attribute__((ext_vector_type(4)));

#define NN 1024

// ---------------- K1: fused ac1 + pair32(relu, pk-f32) + ac2 ----------------
// 512 blocks x 256. Wave owns row i = blk*4+wave.
// x batch (12 KB) staged to LDS once; c1-tiles recomputed from LDS-x (pk);
// j-loop 4-way js split, float2 lanes. Epilogue: row @ W2 -> a2,c2.
__global__ __launch_bounds__(256) void k1_pair32_ac2(
    const float* __restrict__ x,  const float* __restrict__ W1, const float* __restrict__ b1,
    const float* __restrict__ W2, const float* __restrict__ b2,
    float* __restrict__ a2g, float* __restrict__ c2g)
{
    __shared__ float xbuf[3072];        // whole batch x, 12 KB
    __shared__ float cbuf[8192];        // 256 rows x 32, 32 KB
    __shared__ float rowbuf[4][32];

    const int tid  = threadIdx.x;
    const int wave = tid >> 6, lane = tid & 63;
    const int blk  = blockIdx.x;

    const int i  = blk * 4 + wave;      // 0..2047
    const int b  = i >> 10;
    const int il = i & 1023;
    const int js = lane >> 4;           // 0..3 (j-quarter)
    const int fp = lane & 15;           // f-pair index (f = 2fp, 2fp+1)

    // stage x batch to LDS
    const float4v* xb4 = (const float4v*)(x + b * 3072);
    {
        float4v* xd = (float4v*)xbuf;
        #pragma unroll
        for (int n = 0; n < 3; ++n) xd[tid + n * 256] = xb4[tid + n * 256];
    }
    __syncthreads();

    const float xi0 = xbuf[il*3+0], xi1 = xbuf[il*3+1], xi2 = xbuf[il*3+2];
    const float2v* W1v = (const float2v*)W1;
    const float2v* b1v = (const float2v*)b1;
    float2v a  = xi0*W1v[0*16+fp] + xi1*W1v[1*16+fp] + xi2*W1v[2*16+fp];
    float2v cs = xi0*W1v[3*16+fp] + xi1*W1v[4*16+fp] + xi2*W1v[5*16+fp] + b1v[fp];

    // c-recompute assignment: thread (fp2, r0); rows r = r0 + k*16 within tile
    const int fp2 = tid & 15, r0 = tid >> 4;
    const float2v w3 = W1v[3*16+fp2], w4 = W1v[4*16+fp2], w5 = W1v[5*16+fp2];
    const float2v bb = b1v[fp2];

    float2v acc = (float2v)0.f;
    float2v* cb2w = (float2v*)cbuf;
    const float2v* cb2 = (const float2v*)cbuf;
    for (int tile = 0; tile < NN; tile += 256) {
        #pragma unroll
        for (int k = 0; k < 16; ++k) {
            int r = r0 + k * 16;
            int g = tile + r;
            float y0 = xbuf[g*3+0], y1 = xbuf[g*3+1], y2 = xbuf[g*3+2];
            cb2w[r*16 + fp2] = y0*w3 + y1*w4 + y2*w5 + bb;
        }
        __syncthreads();
        #pragma unroll 8
        for (int k = 0; k < 64; ++k) {
            float2v c = cb2[(4*k + js)*16 + fp];
            acc += __builtin_elementwise_max(a + c, (float2v)0.f);
        }
        __syncthreads();
    }
    // reduce across the 4 js groups (lane bits 4,5)
    acc.x += __shfl_xor(acc.x, 16);  acc.y += __shfl_xor(acc.y, 16);
    acc.x += __shfl_xor(acc.x, 32);  acc.y += __shfl_xor(acc.y, 32);

    float2v self = __builtin_elementwise_max(a + cs, (float2v)0.f);
    float2v res  = (acc - self) * (1.0f/1023.0f);
    if (js == 0) ((float2v*)rowbuf[wave])[fp] = res;
    __syncthreads();

    // ---- ac2 epilogue: h-row (32) @ W2 (64x64) + b2 ----
    float av = 0.f, cv = b2[lane];
    #pragma unroll
    for (int d = 0; d < 32; ++d) {
        float hv = rowbuf[wave][d];     // LDS broadcast
        av += hv * W2[d*64 + lane];
        cv += hv * W2[(32 + d)*64 + lane];
    }
    a2g[i*64 + lane] = av;
    c2g[i*64 + lane] = cv;
}

// ---------------- K2: pair-sum F=64 (pk-f32) + fused final projection ----------------
// 512 blocks x 256, 2 blocks/CU. Block owns rows i0..i0+3; ALL 4 waves process
// the same 4 rows, splitting j 8 ways (wave w, lane-half jq): j = 8k + 2w + jq.
// Each ds_read of c[j] feeds 12 pk-VALU (4 rows). Partial accs combined via LDS;
// wave w finalizes row i0+w, projects through W3 (butterfly) -> out, q-partials.
__global__ __launch_bounds__(256) void k2_pair64_final(
    const float* __restrict__ a2g, const float* __restrict__ c2g,
    const float* __restrict__ W3, const float* __restrict__ b3,
    float* __restrict__ out, float* __restrict__ partials)
{
    __shared__ float cbuf[8192];        // 128 j-rows x 64 f, 32 KB
    __shared__ float2v pacc[4][4][32];  // [wave][row][fp], 4 KB
    __shared__ float qpart[4][3];

    const int tid  = threadIdx.x;
    const int wave = tid >> 6, lane = tid & 63;
    const int blk  = blockIdx.x;        // 0..511

    const int i0 = blk * 4;
    const int b  = blk >> 8;            // batch
    const int jq = lane >> 5, fp = lane & 31;

    const float* cb = c2g + b * (NN * 64);
    const float2v* a2v = (const float2v*)a2g;
    const float2v a0 = a2v[(i0+0)*32 + fp];
    const float2v a1 = a2v[(i0+1)*32 + fp];
    const float2v a2 = a2v[(i0+2)*32 + fp];
    const float2v a3 = a2v[(i0+3)*32 + fp];
    float2v s0 = (float2v)0.f, s1 = (float2v)0.f, s2 = (float2v)0.f, s3 = (float2v)0.f;

    const float4v* src = (const float4v*)cb;    // 16 float4 per j-row
    const float2v* cb2 = (const float2v*)cbuf;
    const int jbase = 2*wave + jq;              // this thread's j residue mod 8
    for (int tile = 0; tile < NN; tile += 128) {
        const float4v* sp = src + tile * 16;
        float4v* dst = (float4v*)cbuf;
        #pragma unroll
        for (int n = 0; n < 8; ++n) dst[tid + n*256] = sp[tid + n*256];
        __syncthreads();
        #pragma unroll
        for (int k = 0; k < 16; ++k) {
            float2v c = cb2[(8*k + jbase)*32 + fp];
            s0 += __builtin_elementwise_max(a0 + c, (float2v)0.f);
            s1 += __builtin_elementwise_max(a1 + c, (float2v)0.f);
            s2 += __builtin_elementwise_max(a2 + c, (float2v)0.f);
            s3 += __builtin_elementwise_max(a3 + c, (float2v)0.f);
        }
        __syncthreads();
    }
    // fold jq (lane bit 5)
    s0.x += __shfl_xor(s0.x, 32);  s0.y += __shfl_xor(s0.y, 32);
    s1.x += __shfl_xor(s1.x, 32);  s1.y += __shfl_xor(s1.y, 32);
    s2.x += __shfl_xor(s2.x, 32);  s2.y += __shfl_xor(s2.y, 32);
    s3.x += __shfl_xor(s3.x, 32);  s3.y += __shfl_xor(s3.y, 32);
    if (jq == 0) {
        pacc[wave][0][fp] = s0;  pacc[wave][1][fp] = s1;
        pacc[wave][2][fp] = s2;  pacc[wave][3][fp] = s3;
    }
    __syncthreads();

    // ---- finalize: wave w owns row i0+w ----
    const int i = i0 + wave;
    float2v racc = pacc[0][wave][fp] + pacc[1][wave][fp]
                 + pacc[2][wave][fp] + pacc[3][wave][fp];
    const float2v* cbv = (const float2v*)cb;
    const float inv = 1.0f/1023.0f;
    float2v ai   = a2v[i*32 + fp];
    float2v self = __builtin_elementwise_max(ai + cbv[(i & 1023)*32 + fp], (float2v)0.f);
    float2v res  = (racc - self) * inv;

    // final projection: per-lane f-pair; butterfly within each 32-lane half
    // (both halves hold identical res -> each half's 32-lane sum is the full sum)
    float y[3], q[3];
    #pragma unroll
    for (int t = 0; t < 3; ++t) {
        float wt0 = W3[(2*fp)*3 + t],   wb0 = W3[(64 + 2*fp)*3 + t];
        float wt1 = W3[(2*fp+1)*3 + t], wb1 = W3[(64 + 2*fp+1)*3 + t];
        y[t] = res.x*(wt0 - wb0*inv) + res.y*(wt1 - wb1*inv);
        q[t] = res.x*wb0 + res.y*wb1;
    }
    #pragma unroll
    for (int off = 1; off < 32; off <<= 1) {
        #pragma unroll
        for (int t = 0; t < 3; ++t) {
            y[t] += __shfl_xor(y[t], off);
            q[t] += __shfl_xor(q[t], off);
        }
    }
    if (lane == 0) {
        out[i*3+0] = y[0] + b3[0];
        out[i*3+1] = y[1] + b3[1];
        out[i*3+2] = y[2] + b3[2];
        qpart[wave][0] = q[0];  qpart[wave][1] = q[1];  qpart[wave][2] = q[2];
    }
    __syncthreads();
    if (tid < 3)
        partials[blk*3 + tid] = qpart[0][tid] + qpart[1][tid] + qpart[2][tid] + qpart[3][tid];
}

// ---------------- K3: reduce partials -> S; broadcast add ----------------
// 8 blocks x 256; block blk: batch b=blk>>2, rows (blk&3)*256 + tid of that batch.
__global__ __launch_bounds__(256) void k3_final(
    const float* __restrict__ partials, float* __restrict__ out)
{
    __shared__ float red[4][3];

    const int tid  = threadIdx.x;
    const int wave = tid >> 6, lane = tid & 63;
    const int blk  = blockIdx.x;
    const int b = blk >> 2;

    // 256 threads <-> 256 k2-blocks of this batch
    const float* pb = partials + b * 256 * 3;
    float s0 = pb[tid*3+0], s1 = pb[tid*3+1], s2 = pb[tid*3+2];
    #pragma unroll
    for (int off = 32; off; off >>= 1) {
        s0 += __shfl_xor(s0, off);  s1 += __shfl_xor(s1, off);  s2 += __shfl_xor(s2, off);
    }
    if (lane == 0) { red[wave][0] = s0; red[wave][1] = s1; red[wave][2] = s2; }
    __syncthreads();
    float S0 = (red[0][0]+red[1][0]+red[2][0]+red[3][0]) * (1.0f/1023.0f);
    float S1 = (red[0][1]+red[1][1]+red[2][1]+red[3][1]) * (1.0f/1023.0f);
    float S2 = (red[0][2]+red[1][2]+red[2][2]+red[3][2]) * (1.0f/1023.0f);

    const int i = b * NN + (blk & 3) * 256 + tid;   // global row
    out[i*3+0] += S0;
    out[i*3+1] += S1;
    out[i*3+2] += S2;
}

extern "C" void kernel_launch(void* const* d_in, const int* in_sizes, int n_in,
                              void* d_out, int out_size, void* d_ws, size_t ws_size,
                              hipStream_t stream) {
    const float* x  = (const float*)d_in[0];
    const float* W1 = (const float*)d_in[1];
    const float* b1 = (const float*)d_in[2];
    const float* W2 = (const float*)d_in[3];
    const float* b2 = (const float*)d_in[4];
    const float* W3 = (const float*)d_in[5];
    const float* b3 = (const float*)d_in[6];
    float* out = (float*)d_out;

    float* ws = (float*)d_ws;
    float* a2g      = ws;                    // 131072 floats
    float* c2g      = a2g + 131072;          // 131072 floats
    float* partials = c2g + 131072;          // 1536 floats

    k1_pair32_ac2<<<512, 256, 0, stream>>>(x, W1, b1, W2, b2, a2g, c2g);
    k2_pair64_final<<<512, 256, 0, stream>>>(a2g, c2g, W3, b3, out, partials);
    k3_final<<<8, 256, 0, stream>>>(partials, out);
}